// Round 6
// baseline (33.998 us; speedup 1.0000x reference)
//
#include <hip/hip_runtime.h>
#include <hip/hip_bf16.h>
#include <float.h>

#define VOCAB 128256
#define HID 256
#define NLANG 100
#define BATCH 64
#define SEQ 2048

#define CHUNKS 8
#define TOKB 256                 // tokens per block
#define NTILE (TOKB / 16)        // 16 token-tiles of 16
#define BLOCK 256
#define PADL 128                 // padded lang count (8 lt * 16)
#define APITCH 260               // f32 words per token row in LDS (1040 B: 16B-aligned, 2-way-bank-free)

typedef __attribute__((ext_vector_type(8))) short bf16x8;
typedef __attribute__((ext_vector_type(4))) float f32x4;
typedef __attribute__((ext_vector_type(4))) unsigned int u32x4;

// HW packed cvt: dst.lo = bf16(lo), dst.hi = bf16(hi), RNE
__device__ inline unsigned int cvt_pk_bf16(float lo, float hi) {
    unsigned int r;
    asm("v_cvt_pk_bf16_f32 %0, %1, %2" : "=v"(r) : "v"(lo), "v"(hi));
    return r;
}

// async global->LDS, 16 B per lane; dest = wave-uniform base + lane*16
__device__ inline void gload16(const void* g, void* l) {
    __builtin_amdgcn_global_load_lds(
        (const __attribute__((address_space(1))) void*)g,
        (__attribute__((address_space(3))) void*)l, 16, 0, 0);
}

// Load one B-fragment straight from proj_w (f32) and convert to bf16.
// Fragment (lt,kk,lane) = B[k = kk*32 + (lane>>4)*8 + j][lang = lt*16 + (lane&15)]
__device__ inline bf16x8 load_cvt_b(const float* __restrict__ W, int row, int col) {
    if (row < NLANG) {
        const float* p = W + row * HID + col;
        float4 p0 = *reinterpret_cast<const float4*>(p);
        float4 p1 = *reinterpret_cast<const float4*>(p + 4);
        u32x4 u;
        u[0] = cvt_pk_bf16(p0.x, p0.y); u[1] = cvt_pk_bf16(p0.z, p0.w);
        u[2] = cvt_pk_bf16(p1.x, p1.y); u[3] = cvt_pk_bf16(p1.z, p1.w);
        return __builtin_bit_cast(bf16x8, u);
    }
    return (bf16x8)0;
}

// Kernel 1: per (batch, chunk) block. Token rows DMA'd global->LDS
// (global_load_lds, 4-buffer rotation, depth-2 prefetch, counted vmcnt),
// B-fragments converted in-prologue and held in registers (2 lang-tiles/wave).
// Deadlock audit: uniform control flow; each wave waits only its OWN tile-j
// DMAs (vmcnt(8) of 12 outstanding) then s_barrier publishes all rows; buffer
// (j+2)&3 was last read at tile j-2, which completed before barrier j-1.
// Prologue global loads (proj_w, ids, weights) are fully drained by the
// __syncthreads before issue(0), so loop vmcnt counts ONLY row-DMAs.
__global__ __launch_bounds__(BLOCK, 2) void ld_score_kernel(
    const int* __restrict__ token_ids,
    const float* __restrict__ embeddings,
    const float* __restrict__ token_weights,
    const float* __restrict__ proj_w,
    float* __restrict__ partial)
{
    __shared__ float abuf[4][16][APITCH];   // 66560 B
    __shared__ int   ids_lds[TOKB];         // 1 KB
    __shared__ float wts_lds[TOKB];         // 1 KB

    const int t = threadIdx.x;
    const int lane = t & 63;
    const int wu = __builtin_amdgcn_readfirstlane(t >> 6);
    const int b = blockIdx.x / CHUNKS, chunk = blockIdx.x % CHUNKS;
    const int s0 = chunk * TOKB;

    // ---- stage token ids + weights (keeps vector-global loads OUT of the main loop)
    {
        int id = token_ids[b * SEQ + s0 + t];
        ids_lds[t] = id;
        wts_lds[t] = token_weights[id];
    }

    // ---- B fragments: direct f32 load + cvt (wave wu owns lang-tiles 2wu, 2wu+1)
    const int lt0 = 2 * wu, lt1 = 2 * wu + 1;
    const int brow0 = lt0 * 16 + (lane & 15);
    const int brow1 = lt1 * 16 + (lane & 15);
    const int bcol  = (lane >> 4) * 8;
    bf16x8 b0[8], b1[8];
    #pragma unroll
    for (int kk = 0; kk < 8; ++kk) {
        b0[kk] = load_cvt_b(proj_w, brow0, bcol + kk * 32);
        b1[kk] = load_cvt_b(proj_w, brow1, bcol + kk * 32);
    }

    __syncthreads();   // full drain: B loads + id/wt stores all resolved

    const int tt = lane & 15;   // token within tile (A row, D col-group)
    const int kg = lane >> 4;   // k-group

    // Issue one tile's 16 token-row DMAs; wave wu issues tokens 4wu..4wu+3.
    auto issue = [&](int j) {
        #pragma unroll
        for (int i = 0; i < 4; ++i) {
            int tki = 4 * wu + i;
            int tid = ids_lds[j * 16 + tki];
            const float* g = embeddings + (size_t)tid * HID + lane * 4;
            gload16(g, &abuf[j & 3][tki][0]);
        }
    };

    float rmax0 = -FLT_MAX, rmax1 = -FLT_MAX;

    issue(0);
    issue(1);

    #pragma unroll
    for (int j = 0; j < NTILE; ++j) {
        if (j + 2 < NTILE) issue(j + 2);
        // wait for tile j's DMAs (mine); barrier covers the other waves' shares.
        if (j < NTILE - 2)       asm volatile("s_waitcnt vmcnt(8)" ::: "memory");
        else if (j == NTILE - 2) asm volatile("s_waitcnt vmcnt(4)" ::: "memory");
        else                     asm volatile("s_waitcnt vmcnt(0)" ::: "memory");
        __builtin_amdgcn_s_barrier();

        // per-D-row token weights: D row (token) = kg*4 + r
        float4 wv = *reinterpret_cast<const float4*>(&wts_lds[j * 16 + kg * 4]);

        f32x4 acc0 = {0.f, 0.f, 0.f, 0.f};
        f32x4 acc1 = {0.f, 0.f, 0.f, 0.f};
        #pragma unroll
        for (int kk = 0; kk < 8; ++kk) {
            const float* ap = &abuf[j & 3][tt][kg * 8 + kk * 32];
            float4 p0 = *reinterpret_cast<const float4*>(ap);
            float4 p1 = *reinterpret_cast<const float4*>(ap + 4);
            u32x4 u;
            u[0] = cvt_pk_bf16(p0.x, p0.y); u[1] = cvt_pk_bf16(p0.z, p0.w);
            u[2] = cvt_pk_bf16(p1.x, p1.y); u[3] = cvt_pk_bf16(p1.z, p1.w);
            bf16x8 av = __builtin_bit_cast(bf16x8, u);
            acc0 = __builtin_amdgcn_mfma_f32_16x16x32_bf16(av, b0[kk], acc0, 0, 0, 0);
            acc1 = __builtin_amdgcn_mfma_f32_16x16x32_bf16(av, b1[kk], acc1, 0, 0, 0);
        }
        // D: col(lang)=lane&15, row(token)=kg*4+reg. Scale per-token, then max.
        float m0 = fmaxf(fmaxf(acc0[0] * wv.x, acc0[1] * wv.y),
                         fmaxf(acc0[2] * wv.z, acc0[3] * wv.w));
        float m1 = fmaxf(fmaxf(acc1[0] * wv.x, acc1[1] * wv.y),
                         fmaxf(acc1[2] * wv.z, acc1[3] * wv.w));
        rmax0 = fmaxf(rmax0, m0);
        rmax1 = fmaxf(rmax1, m1);
    }

    // max across the 4 k-groups -> max over all 16 token rows per tile
    rmax0 = fmaxf(rmax0, __shfl_xor(rmax0, 16, 64));
    rmax0 = fmaxf(rmax0, __shfl_xor(rmax0, 32, 64));
    rmax1 = fmaxf(rmax1, __shfl_xor(rmax1, 16, 64));
    rmax1 = fmaxf(rmax1, __shfl_xor(rmax1, 32, 64));

    if (lane < 16) {
        partial[(size_t)blockIdx.x * PADL + lt0 * 16 + lane] = rmax0;
        partial[(size_t)blockIdx.x * PADL + lt1 * 16 + lane] = rmax1;
    }
}

// Kernel 2: reduce chunks, add bias (max(x)+b == max(x+b), b is per-lang).
__global__ void ld_reduce_kernel(const float* __restrict__ partial,
                                 const float* __restrict__ proj_b,
                                 float* __restrict__ out)
{
    const int b = blockIdx.x;
    const int l = threadIdx.x;
    if (l >= NLANG) return;
    float m = -FLT_MAX;
    #pragma unroll
    for (int c = 0; c < CHUNKS; ++c)
        m = fmaxf(m, partial[(size_t)(b * CHUNKS + c) * PADL + l]);
    out[b * NLANG + l] = m + proj_b[l];
}

extern "C" void kernel_launch(void* const* d_in, const int* in_sizes, int n_in,
                              void* d_out, int out_size, void* d_ws, size_t ws_size,
                              hipStream_t stream) {
    const int*   token_ids     = (const int*)d_in[0];
    const float* embeddings    = (const float*)d_in[1];
    const float* token_weights = (const float*)d_in[2];
    const float* proj_w        = (const float*)d_in[3];
    const float* proj_b        = (const float*)d_in[4];
    float* out = (float*)d_out;

    float* partial = (float*)d_ws;   // 512*128*4 = 262144 B

    ld_score_kernel<<<BATCH * CHUNKS, BLOCK, 0, stream>>>(
        token_ids, embeddings, token_weights, proj_w, partial);
    ld_reduce_kernel<<<BATCH, 128, 0, stream>>>(partial, proj_b, out);
}

// Round 8
// 33.810 us; speedup vs baseline: 1.0056x; 1.0056x over previous
//
#include <hip/hip_runtime.h>
#include <hip/hip_bf16.h>
#include <float.h>

#define VOCAB 128256
#define HID 256
#define NLANG 100
#define BATCH 64
#define SEQ 2048

#define CHUNKS 8
#define TOKB 256                 // tokens per block
#define NTILE (TOKB / 16)        // 16 token-tiles of 16
#define BLOCK 256
#define PADL 128                 // padded lang count (8 lt * 16)
#define APITCH 260               // f32 words per token row in LDS (1040 B: 16B-aligned, bank-spread)

typedef __attribute__((ext_vector_type(8))) short bf16x8;
typedef __attribute__((ext_vector_type(4))) float f32x4;
typedef __attribute__((ext_vector_type(4))) unsigned int u32x4;

// HW packed cvt: dst.lo = bf16(lo), dst.hi = bf16(hi), RNE
__device__ inline unsigned int cvt_pk_bf16(float lo, float hi) {
    unsigned int r;
    asm("v_cvt_pk_bf16_f32 %0, %1, %2" : "=v"(r) : "v"(lo), "v"(hi));
    return r;
}

// async global->LDS, 16 B per lane; dest = wave-uniform base + lane*16
__device__ inline void gload16(const void* g, void* l) {
    __builtin_amdgcn_global_load_lds(
        (const __attribute__((address_space(1))) void*)g,
        (__attribute__((address_space(3))) void*)l, 16, 0, 0);
}

// Load one B-fragment straight from proj_w (f32) and convert to bf16.
// Fragment (lt,kk,lane) = B[k = kk*32 + (lane>>4)*8 + j][lang = lt*16 + (lane&15)]
__device__ inline bf16x8 load_cvt_b(const float* __restrict__ W, int row, int col) {
    if (row < NLANG) {
        const float* p = W + row * HID + col;
        float4 p0 = *reinterpret_cast<const float4*>(p);
        float4 p1 = *reinterpret_cast<const float4*>(p + 4);
        u32x4 u;
        u[0] = cvt_pk_bf16(p0.x, p0.y); u[1] = cvt_pk_bf16(p0.z, p0.w);
        u[2] = cvt_pk_bf16(p1.x, p1.y); u[3] = cvt_pk_bf16(p1.z, p1.w);
        return __builtin_bit_cast(bf16x8, u);
    }
    return (bf16x8)0;
}

// Kernel 1: per (batch, chunk) block. Token rows DMA'd global->LDS
// (global_load_lds, 4-buffer rotation, depth-2 prefetch, counted vmcnt),
// B-fragments converted in-prologue and held in registers (2 lang-tiles/wave).
//
// Loop schedule = the PROVEN v5 structure (issue(j+2) BEFORE wait+barrier):
// its safety is position-independent — buffer (j+2)&3's last reader was
// compute(j-2), complete for all waves before the already-passed barrier(j-1),
// so no reliance on compiler ordering around the raw s_barrier. (The v6
// depth-3 issue-after-barrier variant raced: DMA issue drifting above the
// raw s_barrier overwrites a buffer other waves are still reading.)
//
// New vs v5: tiles 0,1 are issued at the TOP of the kernel (ids via
// wave-uniform scalar loads), so their 8 row-DMAs/wave fly under the
// prologue (ids/wts staging + 16 proj_w fragment loads). __syncthreads
// drains everything, so loop vmcnt accounting is exactly v5's.
__global__ __launch_bounds__(BLOCK, 2) void ld_score_kernel(
    const int* __restrict__ token_ids,
    const float* __restrict__ embeddings,
    const float* __restrict__ token_weights,
    const float* __restrict__ proj_w,
    float* __restrict__ partial)
{
    __shared__ float abuf[4][16][APITCH];   // 66560 B
    __shared__ int   ids_lds[TOKB];         // 1 KB
    __shared__ float wts_lds[TOKB];         // 1 KB

    const int t = threadIdx.x;
    const int lane = t & 63;
    const int wu = __builtin_amdgcn_readfirstlane(t >> 6);
    const int b = blockIdx.x / CHUNKS, chunk = blockIdx.x % CHUNKS;
    const int s0 = chunk * TOKB;

    // ---- EARLY ISSUE: tiles 0,1. Wave-uniform scalar id loads; 8 row-DMAs
    // per wave go out before the rest of the prologue's global loads.
    {
        const int* idsrc = token_ids + b * SEQ + s0;
        #pragma unroll
        for (int p = 0; p < 2; ++p) {
            #pragma unroll
            for (int i = 0; i < 4; ++i) {
                int tid = idsrc[p * 16 + 4 * wu + i];   // uniform across lanes
                gload16(embeddings + (size_t)tid * HID + lane * 4,
                        &abuf[p][4 * wu + i][0]);
            }
        }
    }

    // ---- stage token ids + weights (read per-tile by all waves in the loop)
    {
        int id = token_ids[b * SEQ + s0 + t];
        ids_lds[t] = id;
        wts_lds[t] = token_weights[id];
    }

    // ---- B fragments: direct f32 load + cvt (wave wu owns lang-tiles 2wu, 2wu+1)
    const int lt0 = 2 * wu, lt1 = 2 * wu + 1;
    const int brow0 = lt0 * 16 + (lane & 15);
    const int brow1 = lt1 * 16 + (lane & 15);
    const int bcol  = (lane >> 4) * 8;
    bf16x8 b0[8], b1[8];
    #pragma unroll
    for (int kk = 0; kk < 8; ++kk) {
        b0[kk] = load_cvt_b(proj_w, brow0, bcol + kk * 32);
        b1[kk] = load_cvt_b(proj_w, brow1, bcol + kk * 32);
    }

    __syncthreads();   // full drain: early DMAs + B loads + id/wt stores all resolved

    const int tt = lane & 15;   // token within tile (A row, D col-group)
    const int kg = lane >> 4;   // k-group

    // Issue one tile's row-DMAs; wave wu issues tokens 4wu..4wu+3 of the tile.
    auto issue = [&](int j) {
        #pragma unroll
        for (int i = 0; i < 4; ++i) {
            int tki = 4 * wu + i;
            int tid = ids_lds[j * 16 + tki];
            const float* g = embeddings + (size_t)tid * HID + lane * 4;
            gload16(g, &abuf[j & 3][tki][0]);
        }
    };

    float rmax0 = -FLT_MAX, rmax1 = -FLT_MAX;

    #pragma unroll
    for (int j = 0; j < NTILE; ++j) {
        if (j + 2 < NTILE) issue(j + 2);
        // wait for tile j's DMAs (mine); barrier covers the other waves' shares.
        // Counts: tiles 0,1 were drained by __syncthreads; at j>=2 outstanding
        // is tiles j..j+2 (12) -> vmcnt(8) drains tile j. Tails 4/0.
        if (j < NTILE - 2)       asm volatile("s_waitcnt vmcnt(8)" ::: "memory");
        else if (j == NTILE - 2) asm volatile("s_waitcnt vmcnt(4)" ::: "memory");
        else                     asm volatile("s_waitcnt vmcnt(0)" ::: "memory");
        __builtin_amdgcn_s_barrier();

        // per-D-row token weights: D row (token) = kg*4 + r
        float4 wv = *reinterpret_cast<const float4*>(&wts_lds[j * 16 + kg * 4]);

        f32x4 acc0 = {0.f, 0.f, 0.f, 0.f};
        f32x4 acc1 = {0.f, 0.f, 0.f, 0.f};
        #pragma unroll
        for (int kk = 0; kk < 8; ++kk) {
            const float* ap = &abuf[j & 3][tt][kg * 8 + kk * 32];
            float4 p0 = *reinterpret_cast<const float4*>(ap);
            float4 p1 = *reinterpret_cast<const float4*>(ap + 4);
            u32x4 u;
            u[0] = cvt_pk_bf16(p0.x, p0.y); u[1] = cvt_pk_bf16(p0.z, p0.w);
            u[2] = cvt_pk_bf16(p1.x, p1.y); u[3] = cvt_pk_bf16(p1.z, p1.w);
            bf16x8 av = __builtin_bit_cast(bf16x8, u);
            acc0 = __builtin_amdgcn_mfma_f32_16x16x32_bf16(av, b0[kk], acc0, 0, 0, 0);
            acc1 = __builtin_amdgcn_mfma_f32_16x16x32_bf16(av, b1[kk], acc1, 0, 0, 0);
        }
        // D: col(lang)=lane&15, row(token)=kg*4+reg. Scale per-token, then max.
        float m0 = fmaxf(fmaxf(acc0[0] * wv.x, acc0[1] * wv.y),
                         fmaxf(acc0[2] * wv.z, acc0[3] * wv.w));
        float m1 = fmaxf(fmaxf(acc1[0] * wv.x, acc1[1] * wv.y),
                         fmaxf(acc1[2] * wv.z, acc1[3] * wv.w));
        rmax0 = fmaxf(rmax0, m0);
        rmax1 = fmaxf(rmax1, m1);
    }

    // max across the 4 k-groups -> max over all 16 token rows per tile
    rmax0 = fmaxf(rmax0, __shfl_xor(rmax0, 16, 64));
    rmax0 = fmaxf(rmax0, __shfl_xor(rmax0, 32, 64));
    rmax1 = fmaxf(rmax1, __shfl_xor(rmax1, 16, 64));
    rmax1 = fmaxf(rmax1, __shfl_xor(rmax1, 32, 64));

    if (lane < 16) {
        partial[(size_t)blockIdx.x * PADL + lt0 * 16 + lane] = rmax0;
        partial[(size_t)blockIdx.x * PADL + lt1 * 16 + lane] = rmax1;
    }
}

// Kernel 2: reduce chunks, add bias (max(x)+b == max(x+b), b is per-lang).
__global__ void ld_reduce_kernel(const float* __restrict__ partial,
                                 const float* __restrict__ proj_b,
                                 float* __restrict__ out)
{
    const int b = blockIdx.x;
    const int l = threadIdx.x;
    if (l >= NLANG) return;
    float m = -FLT_MAX;
    #pragma unroll
    for (int c = 0; c < CHUNKS; ++c)
        m = fmaxf(m, partial[(size_t)(b * CHUNKS + c) * PADL + l]);
    out[b * NLANG + l] = m + proj_b[l];
}

extern "C" void kernel_launch(void* const* d_in, const int* in_sizes, int n_in,
                              void* d_out, int out_size, void* d_ws, size_t ws_size,
                              hipStream_t stream) {
    const int*   token_ids     = (const int*)d_in[0];
    const float* embeddings    = (const float*)d_in[1];
    const float* token_weights = (const float*)d_in[2];
    const float* proj_w        = (const float*)d_in[3];
    const float* proj_b        = (const float*)d_in[4];
    float* out = (float*)d_out;

    float* partial = (float*)d_ws;   // 512*128*4 = 262144 B

    ld_score_kernel<<<BATCH * CHUNKS, BLOCK, 0, stream>>>(
        token_ids, embeddings, token_weights, proj_w, partial);
    ld_reduce_kernel<<<BATCH, 128, 0, stream>>>(partial, proj_b, out);
}